// Round 2
// baseline (144.662 us; speedup 1.0000x reference)
//
#include <hip/hip_runtime.h>

typedef __bf16 bf16;
typedef __bf16 bf16x4 __attribute__((ext_vector_type(4)));
typedef __bf16 bf16x8 __attribute__((ext_vector_type(8)));
typedef float  f32x16 __attribute__((ext_vector_type(16)));

#define CIN    256
#define KK     9
#define KDIM   2304
#define KSTEPS 144           // KDIM / 16  (K-steps of the 32x32x16 MFMA)
#define PXW    32            // pixels per WG

__device__ __forceinline__ int sreadi(int v) {
    return __builtin_amdgcn_readfirstlane(v);
}

// ---------------------------------------------------------------------------
// Fused prep (unchanged): blocks [0,1024) transpose x -> channels-last bf16;
//             blocks [1024,3328) pack weight -> 32x32x16 A-fragment order:
//   wq[ ((m*144 + ks)*64 + lane)*8 + j ] = W[o = m*32 + (lane&31)]
//                                           [k = ks*16 + (lane>>5)*8 + j]
// ---------------------------------------------------------------------------
__global__ __launch_bounds__(256) void prep_k(const float* __restrict__ x,
                                              const float* __restrict__ w,
                                              bf16* __restrict__ xt,
                                              bf16* __restrict__ wq) {
    int bid = blockIdx.x;
    int tid = threadIdx.x;
    if (bid < 1024) {
        __shared__ bf16 tile[64][72];        // px-major; rows 144 B
        int pt = bid & 63, ct = (bid >> 6) & 3, b = bid >> 8;
        int lane = tid & 63, row = tid >> 6;
        const float* src = x + ((size_t)(b * 256 + ct * 64)) * 4096 + pt * 64;
        #pragma unroll
        for (int cc = row; cc < 64; cc += 4)
            tile[lane][cc] = (bf16)src[(size_t)cc * 4096 + lane];
        __syncthreads();
        bf16* dst = xt + ((size_t)(b * 4096 + pt * 64)) * 256 + ct * 64;
        int p = tid >> 3, j = tid & 7;
        #pragma unroll
        for (int pp = p; pp < 64; pp += 32)
            *reinterpret_cast<bf16x8*>(dst + (size_t)pp * 256 + j * 8) =
                *reinterpret_cast<const bf16x8*>(&tile[pp][j * 8]);
    } else {
        int idx  = (bid - 1024) * 256 + tid;   // < 589824
        int j    = idx & 7;
        int lane = (idx >> 3) & 63;
        int rest = idx >> 9;                   // m*144 + ks, < 1152
        int ks   = rest % KSTEPS;
        int m    = rest / KSTEPS;
        int o    = m * 32 + (lane & 31);
        int k    = ks * 16 + (lane >> 5) * 8 + j;
        int tap  = k >> 8;
        int cc   = k & 255;
        wq[idx] = (bf16)w[(size_t)o * KDIM + cc * KK + tap];
    }
}

// ---------------------------------------------------------------------------
// Fused sampling -> LDS -> 32x32x16 MFMA GEMM, software-pipelined one tap
// ahead (T14 async-split):
//   prologue: PARAMS+ISSUE gathers for tap 0
//   iter t:   COMBINE(t) [consumes gathers issued a full phase ago]
//             -> ds_write S[t&1] -> __syncthreads()
//             -> PARAMS+ISSUE(t+1)  [VMEM flies across GEMM(t) + barrier]
//             -> GEMM(t)            [A-frags loaded in-loop]
// The barrier's vmcnt(0) drain is harmless: the only young memory ops at the
// barrier are the ds_writes; all gathers were issued ~a full phase earlier.
// Sampling params are lane-half-parallel: lane L computes px (L>>5) once
// (halves the redundant wave-uniform VALU chain, removes 8 readfirstlanes);
// each gather load fetches both pixels' 128-ch half (2 x 256 B segments).
// LDS write: b64, both rows per pass, XOR-swizzled -> uniform 4-way
// (= inherent minimum for 512 B). Read side unchanged (0 conflicts, r1).
// Wave (mt = wavei&7, kh = wavei>>3): 32 out-chans x 32 px, K-half kh;
// K-halves summed once through LDS in the epilogue. XCD band swizzle +
// tap rotation kept.
// ---------------------------------------------------------------------------
__global__ __launch_bounds__(1024, 8) void deform_gemm_k(
    const bf16*  __restrict__ xt,
    const float* __restrict__ off,
    const bf16*  __restrict__ wq,
    const float* __restrict__ bias,
    float*       __restrict__ out) {

    __shared__ bf16 S[2][PXW * 256];   // 2 x 16 KB, swizzled 16B granules

    int tid   = threadIdx.x;
    int wavei = sreadi(tid >> 6);   // 0..15
    int lane  = tid & 63;
    int l32   = lane & 31;
    int half  = lane >> 5;
    int mt    = wavei & 7;          // mtile (32 output channels)
    int kh    = wavei >> 3;         // K-half within each tap

    int bid   = blockIdx.x;                      // 0..511
    int pb    = ((bid & 7) << 6) | (bid >> 3);   // XCD-band pixel-block
    int pix0  = pb * PXW;
    int b     = pix0 >> 12;                      // WG-uniform batch
    int pimgb = pix0 & 4095;
    int obase = b * 73728;                       // base into off[]
    int rot   = ((bid >> 3) & 1) * 4;            // co-resident WG desync

    int n     = wavei * 2 + half;                // this lane's S row (0..31)
    int pimg  = pimgb + n;                       // this lane's pixel
    // per-lane gather base: batch + channel slot (l32*4 ch = 8 B)
    const char* xb = (const char*)xt + ((size_t)b << 21) + (unsigned)(l32 * 8);

    f32x16 acc;
    #pragma unroll
    for (int r = 0; r < 16; ++r) acc[r] = 0.f;

    // pipeline state: tap t+1's weights + in-flight gather data
    float wt[4];
    uint2 g[8];                                   // [corner*2 + pass]

    auto sample_issue = [&](int tp) {
        int ty = tp / 3 - 1;
        int tx = tp % 3 - 1;
        float oy = off[obase + (2 * tp) * 4096 + pimg];
        float ox = off[obase + (2 * tp + 1) * 4096 + pimg];
        float py = (float)((pimg >> 6) + ty) + oy;
        float px = (float)((pimg & 63) + tx) + ox;
        float fy = floorf(py), fx = floorf(px);
        int   y0 = (int)fy,    x0 = (int)fx;
        float wy1 = py - fy, wx1 = px - fx;
        float wy0 = 1.f - wy1, wx0 = 1.f - wx1;
        wy0 = ((unsigned)y0       < 64u) ? wy0 : 0.f;
        wy1 = ((unsigned)(y0 + 1) < 64u) ? wy1 : 0.f;
        wx0 = ((unsigned)x0       < 64u) ? wx0 : 0.f;
        wx1 = ((unsigned)(x0 + 1) < 64u) ? wx1 : 0.f;
        int yc0 = min(max(y0, 0), 63), yc1 = min(max(y0 + 1, 0), 63);
        int xc0 = min(max(x0, 0), 63), xc1 = min(max(x0 + 1, 0), 63);
        unsigned u0 = (unsigned)(yc0 * 64 + xc0) * 512u;
        unsigned u1 = (unsigned)(yc0 * 64 + xc1) * 512u;
        unsigned u2 = (unsigned)(yc1 * 64 + xc0) * 512u;
        unsigned u3 = (unsigned)(yc1 * 64 + xc1) * 512u;
        wt[0] = wy0 * wx0; wt[1] = wy0 * wx1;
        wt[2] = wy1 * wx0; wt[3] = wy1 * wx1;
        g[0] = *reinterpret_cast<const uint2*>(xb + u0);
        g[1] = *reinterpret_cast<const uint2*>(xb + u0 + 256);
        g[2] = *reinterpret_cast<const uint2*>(xb + u1);
        g[3] = *reinterpret_cast<const uint2*>(xb + u1 + 256);
        g[4] = *reinterpret_cast<const uint2*>(xb + u2);
        g[5] = *reinterpret_cast<const uint2*>(xb + u2 + 256);
        g[6] = *reinterpret_cast<const uint2*>(xb + u3);
        g[7] = *reinterpret_cast<const uint2*>(xb + u3 + 256);
    };

    int tapc = rot;            // tap(0)
    sample_issue(tapc);        // prologue: params + gathers for tap 0

    for (int t = 0; t < KK; ++t) {
        bf16* Sw = &S[t & 1][0];

        // ---- COMBINE(t): bilinear-blend in-flight gathers, write S ----
        #pragma unroll
        for (int p = 0; p < 2; ++p) {
            float a0 = 0.f, a1 = 0.f, a2 = 0.f, a3 = 0.f;
            #pragma unroll
            for (int c = 0; c < 4; ++c) {
                uint2 v = g[c * 2 + p];
                float f0 = __builtin_bit_cast(float, v.x << 16);
                float f1 = __builtin_bit_cast(float, v.x & 0xffff0000u);
                float f2 = __builtin_bit_cast(float, v.y << 16);
                float f3 = __builtin_bit_cast(float, v.y & 0xffff0000u);
                a0 = fmaf(wt[c], f0, a0);
                a1 = fmaf(wt[c], f1, a1);
                a2 = fmaf(wt[c], f2, a2);
                a3 = fmaf(wt[c], f3, a3);
            }
            bf16x4 sv;
            sv[0] = (bf16)a0; sv[1] = (bf16)a1;
            sv[2] = (bf16)a2; sv[3] = (bf16)a3;
            // ch = p*128 + (l32)*4 -> granule p*16 + (l32>>1), 8B half l32&1
            int gsw = ((p * 16) + (l32 >> 1)) ^ n;
            *reinterpret_cast<bf16x4*>(Sw + n * 256 + gsw * 8 + (l32 & 1) * 4) = sv;
        }

        __syncthreads();       // S[t&1] ready; only ds_writes are young here

        int tapg = tapc;       // tap for GEMM(t)
        if (t < KK - 1) {      // PARAMS + ISSUE for tap t+1 (fly across GEMM)
            int tn = tapc + 1; if (tn >= KK) tn = 0;
            tapc = tn;
            sample_issue(tn);
        }

        // ---- GEMM(t) over this wave's K-half (128 of the tap's 256) ----
        const bf16* Sr  = Sw;
        const bf16* ap0 = wq +
            ((size_t)(((mt * KSTEPS) + tapg * 16 + kh * 8) * 64 + lane)) * 8;
        #pragma unroll
        for (int kk2 = 0; kk2 < 8; ++kk2) {
            bf16x8 a = *reinterpret_cast<const bf16x8*>(ap0 + (size_t)kk2 * 512);
            int gg  = (kh * 8 + kk2) * 2 + half;    // 16B granule index
            int gsr = gg ^ l32;                     // row = l32
            bf16x8 bv = *reinterpret_cast<const bf16x8*>(Sr + l32 * 256 + gsr * 8);
            acc = __builtin_amdgcn_mfma_f32_32x32x16_bf16(a, bv, acc, 0, 0, 0);
        }
        // next tap writes the OTHER buffer; re-write of this buffer (t+2)
        // is ordered behind barrier t+1 (reads(t) precede it in prog order).
    }

    // ---- epilogue: sum the two K-halves through LDS, then store ----
    __syncthreads();                 // all GEMM reads of S done
    float* Sf = reinterpret_cast<float*>(&S[0][0]);   // 8192 f32 = 32 KB
    if (wavei >= 8) {
        int wb = (wavei - 8) * 64 + lane;
        #pragma unroll
        for (int r = 0; r < 16; ++r)
            Sf[r * 512 + wb] = acc[r];   // lane-major: conflict-free b32
    }
    __syncthreads();
    if (wavei < 8) {
        // C/D layout (32x32x16): col = lane&31, row = (r&3)+8*(r>>2)+4*half
        int wb   = wavei * 64 + lane;
        int m    = mt * 32;              // mt == wavei here (kh == 0)
        int pimo = pimgb + l32;
        float* op = out + ((size_t)(b * 256 + m)) * 4096 + pimo;
        #pragma unroll
        for (int r = 0; r < 16; ++r) {
            int row = (r & 3) + 8 * (r >> 2) + half * 4;
            float v = acc[r] + Sf[r * 512 + wb] + bias[m + row];
            op[(size_t)row * 4096] = v;
        }
    }
}

// ---------------------------------------------------------------------------
extern "C" void kernel_launch(void* const* d_in, const int* in_sizes, int n_in,
                              void* d_out, int out_size, void* d_ws, size_t ws_size,
                              hipStream_t stream) {
    const float* x    = (const float*)d_in[0];   // [4,256,64,64]
    const float* off  = (const float*)d_in[1];   // [4,18,64,64]
    const float* w    = (const float*)d_in[2];   // [256,256,3,3]
    const float* bias = (const float*)d_in[3];   // [256]
    float* out = (float*)d_out;                  // [4,256,64,64]

    bf16* wq = (bf16*)d_ws;                               // 1,179,648 B
    bf16* xt = (bf16*)((char*)d_ws + (size_t)589824 * 2); // 8,388,608 B

    prep_k<<<3328, 256, 0, stream>>>(x, w, xt, wq);
    deform_gemm_k<<<512, 1024, 0, stream>>>(xt, off, wq, bias, out);
}